// Round 4
// baseline (316.875 us; speedup 1.0000x reference)
//
#include <hip/hip_runtime.h>

// SimpleGNN on MI355X — fp32 in/out, edge_index int32/int64 auto-detect.
// out[d] = di[d]*(S[d] @ M) + di[d]*cnt_col[d]*c + b2
//   M = W1^T W2^T [128x64], c = b1 @ W2^T [64]
//   S[d] = sum_{e: col_e=d} x[row_e],  di[d] = 1/deg_row[d] (0 if deg 0)
// Zero global atomics: LDS-privatized histograms + counting-sort CSR build.

#define IN_CH   128
#define OUT_CH  64
#define SCAN_B  256
#define NCHUNK  16     // edge chunks
#define NRANGE  4      // node ranges
#define RBINS   12800  // bins per range (supports n_nodes <= 51200), 51.2 KB LDS

// -------- kernel 1: M = W1^T W2^T, c = b1 @ W2^T, + int64-detect flag --------
__global__ __launch_bounds__(256) void mk_M_c(const float* __restrict__ W1,
                                              const float* __restrict__ b1,
                                              const float* __restrict__ W2,
                                              const int* __restrict__ ei,
                                              float* __restrict__ M,   // [128*64]
                                              float* __restrict__ c,   // [64]
                                              int* __restrict__ flag) {
    int tid = blockIdx.x * blockDim.x + threadIdx.x;
    if (tid < IN_CH * OUT_CH) {
        int o = tid & (OUT_CH - 1);
        int i = tid >> 6;
        float acc = 0.f;
        for (int h = 0; h < 128; ++h)
            acc += W1[h * 128 + i] * W2[o * 128 + h];
        M[i * OUT_CH + o] = acc;
    } else if (tid < IN_CH * OUT_CH + OUT_CH) {
        int o = tid - IN_CH * OUT_CH;
        float acc = 0.f;
        for (int h = 0; h < 128; ++h)
            acc += b1[h] * W2[o * 128 + h];
        c[o] = acc;
    } else if (tid == IN_CH * OUT_CH + OUT_CH) {
        // int64 edge_index => odd int32 words are all 0 (values < 2^31)
        int f = 1;
        for (int i = 1; i < 64; i += 2)
            if (ei[i] != 0) { f = 0; break; }
        *flag = f;   // 1 = int64 (stride 2), 0 = int32
    }
}

// -------- per-(chunk,range,array) LDS histogram -> slabs (plain stores) --------
// row slab: counts of row values (deg). col slab: counts of col values where
// BOTH endpoints valid (matches CSR contents).
__global__ __launch_bounds__(256) void mk_hist(const int* __restrict__ ei,
                                               const int* __restrict__ flag,
                                               int* __restrict__ row_slab,  // [NCHUNK][n_nodes]
                                               int* __restrict__ col_slab,  // [NCHUNK][n_nodes]
                                               int n_edges, int n_nodes) {
    __shared__ int bins[RBINS];
    int b = blockIdx.x;
    int chunk = b % NCHUNK;
    int range = (b / NCHUNK) % NRANGE;
    int arr   = b / (NCHUNK * NRANGE);   // 0 = row, 1 = col

    int range_size = (n_nodes + NRANGE - 1) / NRANGE;
    int lo = range * range_size;
    int hi = lo + range_size; if (hi > n_nodes) hi = n_nodes;
    int nbins = hi - lo;

    for (int i = threadIdx.x; i < nbins; i += 256) bins[i] = 0;
    __syncthreads();

    int stride = 1 + *flag;
    size_t e0 = (size_t)chunk * n_edges / NCHUNK;
    size_t e1 = (size_t)(chunk + 1) * n_edges / NCHUNK;

    if (arr == 0) {
        for (size_t e = e0 + threadIdx.x; e < e1; e += 256) {
            int r = ei[e * stride];
            if ((unsigned)r < (unsigned)n_nodes && r >= lo && r < hi)
                atomicAdd(&bins[r - lo], 1);
        }
    } else {
        for (size_t e = e0 + threadIdx.x; e < e1; e += 256) {
            int s = ei[e * stride];
            int d = ei[((size_t)n_edges + e) * stride];
            if ((unsigned)s < (unsigned)n_nodes && (unsigned)d < (unsigned)n_nodes
                && d >= lo && d < hi)
                atomicAdd(&bins[d - lo], 1);
        }
    }
    __syncthreads();

    int* slab = (arr == 0) ? row_slab : col_slab;
    size_t base = (size_t)chunk * n_nodes + lo;
    for (int i = threadIdx.x; i < nbins; i += 256)
        slab[base + i] = bins[i];
}

// -------- per-node: sum slabs -> deg_row / cnt_col; excl-scan col slab --------
__global__ __launch_bounds__(256) void mk_chunkoff(int* __restrict__ row_slab,
                                                   int* __restrict__ col_slab,
                                                   int* __restrict__ deg_row,
                                                   int* __restrict__ cnt_col,
                                                   int n_nodes) {
    int n = blockIdx.x * 256 + threadIdx.x;
    if (n >= n_nodes) return;
    int sum = 0;
#pragma unroll
    for (int ch = 0; ch < NCHUNK; ++ch)
        sum += row_slab[(size_t)ch * n_nodes + n];
    deg_row[n] = sum;
    int run = 0;
#pragma unroll
    for (int ch = 0; ch < NCHUNK; ++ch) {
        int v = col_slab[(size_t)ch * n_nodes + n];
        col_slab[(size_t)ch * n_nodes + n] = run;   // exclusive offset of chunk in bin
        run += v;
    }
    cnt_col[n] = run;
}

// -------- scan: exclusive prefix sum of cnt_col -> cursor --------
__global__ __launch_bounds__(SCAN_B) void scanA(const int* __restrict__ cnt,
                                                int* __restrict__ cursor,
                                                int* __restrict__ bsums, int n) {
    __shared__ int s[SCAN_B];
    int t = threadIdx.x;
    int i = blockIdx.x * SCAN_B + t;
    int v = (i < n) ? cnt[i] : 0;
    s[t] = v;
    __syncthreads();
    for (int d = 1; d < SCAN_B; d <<= 1) {
        int add = (t >= d) ? s[t - d] : 0;
        __syncthreads();
        s[t] += add;
        __syncthreads();
    }
    if (i < n) cursor[i] = s[t] - v;
    if (t == SCAN_B - 1) bsums[blockIdx.x] = s[t];
}

__global__ __launch_bounds__(SCAN_B) void scanB(int* __restrict__ bsums, int nb) {
    int t = threadIdx.x;
    if (nb > SCAN_B) {
        if (t == 0) {
            int run = 0;
            for (int j = 0; j < nb; ++j) { int x = bsums[j]; bsums[j] = run; run += x; }
        }
        return;
    }
    __shared__ int s[SCAN_B];
    int v = (t < nb) ? bsums[t] : 0;
    s[t] = v;
    __syncthreads();
    for (int d = 1; d < SCAN_B; d <<= 1) {
        int add = (t >= d) ? s[t - d] : 0;
        __syncthreads();
        s[t] += add;
        __syncthreads();
    }
    if (t < nb) bsums[t] = s[t] - v;
}

__global__ __launch_bounds__(SCAN_B) void scanC(int* __restrict__ cursor,
                                                const int* __restrict__ bsums, int n) {
    int i = blockIdx.x * SCAN_B + threadIdx.x;
    if (i < n) cursor[i] += bsums[blockIdx.x];
}

// -------- counting-sort placement: plain stores, no global atomics --------
__global__ __launch_bounds__(256) void mk_place(const int* __restrict__ ei,
                                                const int* __restrict__ flag,
                                                const int* __restrict__ cursor,    // excl bin starts
                                                const int* __restrict__ col_slab,  // chunk offsets
                                                int* __restrict__ csr_src,
                                                int n_edges, int n_nodes) {
    __shared__ int rank[RBINS];
    int b = blockIdx.x;
    int chunk = b % NCHUNK;
    int range = b / NCHUNK;

    int range_size = (n_nodes + NRANGE - 1) / NRANGE;
    int lo = range * range_size;
    int hi = lo + range_size; if (hi > n_nodes) hi = n_nodes;

    for (int i = threadIdx.x; i < hi - lo; i += 256) rank[i] = 0;
    __syncthreads();

    int stride = 1 + *flag;
    size_t e0 = (size_t)chunk * n_edges / NCHUNK;
    size_t e1 = (size_t)(chunk + 1) * n_edges / NCHUNK;

    for (size_t e = e0 + threadIdx.x; e < e1; e += 256) {
        int s = ei[e * stride];
        int d = ei[((size_t)n_edges + e) * stride];
        if ((unsigned)s < (unsigned)n_nodes && (unsigned)d < (unsigned)n_nodes
            && d >= lo && d < hi) {
            int r = atomicAdd(&rank[d - lo], 1);
            int slot = cursor[d] + col_slab[(size_t)chunk * n_nodes + d] + r;
            csr_src[slot] = s;
        }
    }
}

// -------- kernel: y = x @ M, 64x64 tile, 4x4 register micro-tile --------
__global__ __launch_bounds__(256) void mk_y(const float* __restrict__ x,
                                            const float* __restrict__ M,
                                            float* __restrict__ y,
                                            int n_nodes) {
    __shared__ float Ms[IN_CH * OUT_CH];   // 32 KB
    __shared__ float xs[64][IN_CH + 4];
    int tid = threadIdx.x;
    int tx = tid & 15;
    int ty = tid >> 4;
    int row0 = blockIdx.x * 64;

    const float4* Mv = (const float4*)M;
    float4* Msv = (float4*)Ms;
#pragma unroll
    for (int k = 0; k < 8; ++k) Msv[tid + 256 * k] = Mv[tid + 256 * k];

    for (int f = tid; f < 64 * 32; f += 256) {
        int r = f >> 5, kq = f & 31;
        float4 v = make_float4(0.f, 0.f, 0.f, 0.f);
        if (row0 + r < n_nodes)
            v = *(const float4*)&x[(size_t)(row0 + r) * IN_CH + 4 * kq];
        *(float4*)&xs[r][4 * kq] = v;
    }
    __syncthreads();

    float4 acc[4];
#pragma unroll
    for (int j = 0; j < 4; ++j) acc[j] = make_float4(0.f, 0.f, 0.f, 0.f);

    for (int k = 0; k < IN_CH; k += 4) {
        float4 xr[4], mr[4];
#pragma unroll
        for (int j = 0; j < 4; ++j)
            xr[j] = *(const float4*)&xs[4 * ty + j][k];
#pragma unroll
        for (int kk = 0; kk < 4; ++kk)
            mr[kk] = *(const float4*)&Ms[(k + kk) * OUT_CH + 4 * tx];
#pragma unroll
        for (int j = 0; j < 4; ++j) {
            acc[j].x = fmaf(xr[j].x, mr[0].x, acc[j].x);
            acc[j].y = fmaf(xr[j].x, mr[0].y, acc[j].y);
            acc[j].z = fmaf(xr[j].x, mr[0].z, acc[j].z);
            acc[j].w = fmaf(xr[j].x, mr[0].w, acc[j].w);
            acc[j].x = fmaf(xr[j].y, mr[1].x, acc[j].x);
            acc[j].y = fmaf(xr[j].y, mr[1].y, acc[j].y);
            acc[j].z = fmaf(xr[j].y, mr[1].z, acc[j].z);
            acc[j].w = fmaf(xr[j].y, mr[1].w, acc[j].w);
            acc[j].x = fmaf(xr[j].z, mr[2].x, acc[j].x);
            acc[j].y = fmaf(xr[j].z, mr[2].y, acc[j].y);
            acc[j].z = fmaf(xr[j].z, mr[2].z, acc[j].z);
            acc[j].w = fmaf(xr[j].z, mr[2].w, acc[j].w);
            acc[j].x = fmaf(xr[j].w, mr[3].x, acc[j].x);
            acc[j].y = fmaf(xr[j].w, mr[3].y, acc[j].y);
            acc[j].z = fmaf(xr[j].w, mr[3].z, acc[j].z);
            acc[j].w = fmaf(xr[j].w, mr[3].w, acc[j].w);
        }
    }

#pragma unroll
    for (int j = 0; j < 4; ++j) {
        int r = row0 + 4 * ty + j;
        if (r < n_nodes)
            *(float4*)&y[(size_t)r * OUT_CH + 4 * tx] = acc[j];
    }
}

// -------- gather-sum + finalize: one wave per dst node --------
__global__ __launch_bounds__(256) void mk_agg_final(const int* __restrict__ cursor,  // excl starts
                                                    const int* __restrict__ cnt_col,
                                                    const int* __restrict__ csr_src,
                                                    const int* __restrict__ deg_row,
                                                    const float* __restrict__ y,
                                                    const float* __restrict__ c,
                                                    const float* __restrict__ b2,
                                                    float* __restrict__ out,
                                                    int n_nodes) {
    int wave = threadIdx.x >> 6;
    int lane = threadIdx.x & 63;
    int d = blockIdx.x * 4 + wave;
    if (d >= n_nodes) return;
    int start = cursor[d];
    int cnt = cnt_col[d];
    int end = start + cnt;
    float acc = 0.f;
    int j = start;
    for (; j + 3 < end; j += 4) {
        int s0 = csr_src[j];
        int s1 = csr_src[j + 1];
        int s2 = csr_src[j + 2];
        int s3 = csr_src[j + 3];
        float v0 = y[(size_t)s0 * OUT_CH + lane];
        float v1 = y[(size_t)s1 * OUT_CH + lane];
        float v2 = y[(size_t)s2 * OUT_CH + lane];
        float v3 = y[(size_t)s3 * OUT_CH + lane];
        acc += (v0 + v1) + (v2 + v3);
    }
    for (; j < end; ++j)
        acc += y[(size_t)csr_src[j] * OUT_CH + lane];
    int dr = deg_row[d];
    float di = (dr > 0) ? (1.0f / (float)dr) : 0.f;
    out[(size_t)d * OUT_CH + lane] = di * acc + di * (float)cnt * c[lane] + b2[lane];
}

extern "C" void kernel_launch(void* const* d_in, const int* in_sizes, int n_in,
                              void* d_out, int out_size, void* d_ws, size_t ws_size,
                              hipStream_t stream) {
    const float* x  = (const float*)d_in[0];
    const int*   ei = (const int*)d_in[1];
    const float* W1 = (const float*)d_in[2];
    const float* b1 = (const float*)d_in[3];
    const float* W2 = (const float*)d_in[4];
    const float* b2 = (const float*)d_in[5];
    float* out = (float*)d_out;

    const int n_nodes = in_sizes[0] / IN_CH;     // 50000
    const int n_edges = in_sizes[1] / 2;         // 800000

    const size_t slab_bytes = (size_t)NCHUNK * n_nodes * sizeof(int);  // 3.2 MB

    char* ws = (char*)d_ws;
    float* M        = (float*)(ws);                    // 32768
    float* c        = (float*)(ws + 32768);            // 256
    int*   flag     = (int*)  (ws + 33024);            // 128
    int*   deg_row  = (int*)  (ws + 33152);            // 200064
    int*   cnt_col  = (int*)  (ws + 233216);           // 200064
    int*   cursor   = (int*)  (ws + 433280);           // 200064
    int*   bsums    = (int*)  (ws + 633344);           // 1024
    int*   row_slab = (int*)  (ws + 634368);
    int*   col_slab = (int*)  (ws + 634368 + slab_bytes);
    int*   csr_src  = (int*)  (ws + 634368 + 2 * slab_bytes);
    float* y        = (float*)(ws + 634368 + 2 * slab_bytes + (size_t)n_edges * 4);

    mk_M_c<<<(IN_CH * OUT_CH + OUT_CH + 1 + 255) / 256, 256, 0, stream>>>(
        W1, b1, W2, ei, M, c, flag);

    mk_hist<<<NCHUNK * NRANGE * 2, 256, 0, stream>>>(ei, flag, row_slab, col_slab,
                                                     n_edges, n_nodes);

    mk_chunkoff<<<(n_nodes + 255) / 256, 256, 0, stream>>>(row_slab, col_slab,
                                                           deg_row, cnt_col, n_nodes);

    int nb = (n_nodes + SCAN_B - 1) / SCAN_B;    // 196
    scanA<<<nb, SCAN_B, 0, stream>>>(cnt_col, cursor, bsums, n_nodes);
    scanB<<<1, SCAN_B, 0, stream>>>(bsums, nb);
    scanC<<<nb, SCAN_B, 0, stream>>>(cursor, bsums, n_nodes);

    mk_place<<<NCHUNK * NRANGE, 256, 0, stream>>>(ei, flag, cursor, col_slab,
                                                  csr_src, n_edges, n_nodes);

    mk_y<<<(n_nodes + 63) / 64, 256, 0, stream>>>(x, M, y, n_nodes);

    mk_agg_final<<<(n_nodes + 3) / 4, 256, 0, stream>>>(cursor, cnt_col, csr_src,
                                                        deg_row, y, c, b2, out, n_nodes);
}

// Round 5
// 270.537 us; speedup vs baseline: 1.1713x; 1.1713x over previous
//
#include <hip/hip_runtime.h>

// SimpleGNN on MI355X — fp32 in/out, edge_index int32/int64 auto-detect.
// out[d] = di[d]*(S[d] @ M) + di[d]*cnt_col[d]*c + b2
//   M = W1^T W2^T [128x64], c = b1 @ W2^T [64]
//   S[d] = sum_{e: col_e=d} x[row_e],  di[d] = 1/deg_row[d] (0 if deg 0)
// Zero global atomics: LDS-privatized histograms + counting-sort CSR build.
// R4 lesson: hist/place need >=256 blocks & small LDS for occupancy.

#define IN_CH   128
#define OUT_CH  64
#define SCAN_B  256
#define NCHUNK  32     // edge chunks
#define NRANGE  8      // node ranges
#define RBINS   6272   // bins per range (n_nodes <= 50176), 25 KB LDS

typedef unsigned short u16;

// -------- kernel 1: M = W1^T W2^T, c = b1 @ W2^T, + int64-detect flag --------
__global__ __launch_bounds__(256) void mk_M_c(const float* __restrict__ W1,
                                              const float* __restrict__ b1,
                                              const float* __restrict__ W2,
                                              const int* __restrict__ ei,
                                              float* __restrict__ M,   // [128*64]
                                              float* __restrict__ c,   // [64]
                                              int* __restrict__ flag) {
    int tid = blockIdx.x * blockDim.x + threadIdx.x;
    if (tid < IN_CH * OUT_CH) {
        int o = tid & (OUT_CH - 1);
        int i = tid >> 6;
        float acc = 0.f;
        for (int h = 0; h < 128; ++h)
            acc += W1[h * 128 + i] * W2[o * 128 + h];
        M[i * OUT_CH + o] = acc;
    } else if (tid < IN_CH * OUT_CH + OUT_CH) {
        int o = tid - IN_CH * OUT_CH;
        float acc = 0.f;
        for (int h = 0; h < 128; ++h)
            acc += b1[h] * W2[o * 128 + h];
        c[o] = acc;
    } else if (tid == IN_CH * OUT_CH + OUT_CH) {
        // int64 edge_index => odd int32 words all 0 (values < 2^31)
        int f = 1;
        for (int i = 1; i < 64; i += 2)
            if (ei[i] != 0) { f = 0; break; }
        *flag = f;   // 1 = int64 (stride 2), 0 = int32
    }
}

// -------- per-(chunk,range,array) LDS histogram -> u16 slabs --------
// arr 0: counts of row values (deg). arr 1: counts of col values where BOTH
// endpoints valid (matches CSR contents).
__global__ __launch_bounds__(256) void mk_hist(const int* __restrict__ ei,
                                               const int* __restrict__ flag,
                                               u16* __restrict__ row_slab,  // [NCHUNK][n_nodes]
                                               u16* __restrict__ col_slab,  // [NCHUNK][n_nodes]
                                               int n_edges, int n_nodes) {
    __shared__ int bins[RBINS];
    int b = blockIdx.x;
    int chunk = b & (NCHUNK - 1);
    int range = (b >> 5) & (NRANGE - 1);
    int arr   = b >> 8;                  // 0 = row, 1 = col

    int range_size = (n_nodes + NRANGE - 1) / NRANGE;
    int lo = range * range_size;
    int hi = lo + range_size; if (hi > n_nodes) hi = n_nodes;
    int nbins = hi - lo;
    if (nbins <= 0) return;

    for (int i = threadIdx.x; i < nbins; i += 256) bins[i] = 0;
    __syncthreads();

    int stride = 1 + *flag;
    size_t e0 = (size_t)chunk * n_edges / NCHUNK;
    size_t e1 = (size_t)(chunk + 1) * n_edges / NCHUNK;

    if (arr == 0) {
        for (size_t e = e0 + threadIdx.x; e < e1; e += 256) {
            int r = ei[e * stride];
            if ((unsigned)r < (unsigned)n_nodes && r >= lo && r < hi)
                atomicAdd(&bins[r - lo], 1);
        }
    } else {
        for (size_t e = e0 + threadIdx.x; e < e1; e += 256) {
            int d = ei[((size_t)n_edges + e) * stride];
            if ((unsigned)d < (unsigned)n_nodes && d >= lo && d < hi) {
                int s = ei[e * stride];
                if ((unsigned)s < (unsigned)n_nodes)
                    atomicAdd(&bins[d - lo], 1);
            }
        }
    }
    __syncthreads();

    u16* slab = (arr == 0) ? row_slab : col_slab;
    size_t base = (size_t)chunk * n_nodes + lo;
    for (int i = threadIdx.x; i < nbins; i += 256)
        slab[base + i] = (u16)bins[i];
}

// -------- per-node: sum slabs -> deg_row / cnt_col; excl-scan col slab --------
__global__ __launch_bounds__(256) void mk_chunkoff(u16* __restrict__ row_slab,
                                                   u16* __restrict__ col_slab,
                                                   int* __restrict__ deg_row,
                                                   int* __restrict__ cnt_col,
                                                   int n_nodes) {
    int n = blockIdx.x * 256 + threadIdx.x;
    if (n >= n_nodes) return;
    int sum = 0;
#pragma unroll
    for (int ch = 0; ch < NCHUNK; ++ch)
        sum += row_slab[(size_t)ch * n_nodes + n];
    deg_row[n] = sum;
    int run = 0;
#pragma unroll
    for (int ch = 0; ch < NCHUNK; ++ch) {
        int v = col_slab[(size_t)ch * n_nodes + n];
        col_slab[(size_t)ch * n_nodes + n] = (u16)run;  // excl offset of chunk in bin
        run += v;
    }
    cnt_col[n] = run;
}

// -------- scan: exclusive prefix sum of cnt_col -> cursor --------
__global__ __launch_bounds__(SCAN_B) void scanA(const int* __restrict__ cnt,
                                                int* __restrict__ cursor,
                                                int* __restrict__ bsums, int n) {
    __shared__ int s[SCAN_B];
    int t = threadIdx.x;
    int i = blockIdx.x * SCAN_B + t;
    int v = (i < n) ? cnt[i] : 0;
    s[t] = v;
    __syncthreads();
    for (int d = 1; d < SCAN_B; d <<= 1) {
        int add = (t >= d) ? s[t - d] : 0;
        __syncthreads();
        s[t] += add;
        __syncthreads();
    }
    if (i < n) cursor[i] = s[t] - v;
    if (t == SCAN_B - 1) bsums[blockIdx.x] = s[t];
}

__global__ __launch_bounds__(SCAN_B) void scanB(int* __restrict__ bsums, int nb) {
    int t = threadIdx.x;
    if (nb > SCAN_B) {
        if (t == 0) {
            int run = 0;
            for (int j = 0; j < nb; ++j) { int x = bsums[j]; bsums[j] = run; run += x; }
        }
        return;
    }
    __shared__ int s[SCAN_B];
    int v = (t < nb) ? bsums[t] : 0;
    s[t] = v;
    __syncthreads();
    for (int d = 1; d < SCAN_B; d <<= 1) {
        int add = (t >= d) ? s[t - d] : 0;
        __syncthreads();
        s[t] += add;
        __syncthreads();
    }
    if (t < nb) bsums[t] = s[t] - v;
}

__global__ __launch_bounds__(SCAN_B) void scanC(int* __restrict__ cursor,
                                                const int* __restrict__ bsums, int n) {
    int i = blockIdx.x * SCAN_B + threadIdx.x;
    if (i < n) cursor[i] += bsums[blockIdx.x];
}

// -------- counting-sort placement: plain stores, no global atomics --------
__global__ __launch_bounds__(256) void mk_place(const int* __restrict__ ei,
                                                const int* __restrict__ flag,
                                                const int* __restrict__ cursor,    // excl bin starts
                                                const u16* __restrict__ col_slab,  // chunk offsets
                                                int* __restrict__ csr_src,
                                                int n_edges, int n_nodes) {
    __shared__ int rank[RBINS];
    int b = blockIdx.x;
    int chunk = b & (NCHUNK - 1);
    int range = b >> 5;

    int range_size = (n_nodes + NRANGE - 1) / NRANGE;
    int lo = range * range_size;
    int hi = lo + range_size; if (hi > n_nodes) hi = n_nodes;
    if (hi <= lo) return;

    for (int i = threadIdx.x; i < hi - lo; i += 256) rank[i] = 0;
    __syncthreads();

    int stride = 1 + *flag;
    size_t e0 = (size_t)chunk * n_edges / NCHUNK;
    size_t e1 = (size_t)(chunk + 1) * n_edges / NCHUNK;

    for (size_t e = e0 + threadIdx.x; e < e1; e += 256) {
        int d = ei[((size_t)n_edges + e) * stride];
        if ((unsigned)d < (unsigned)n_nodes && d >= lo && d < hi) {
            int s = ei[e * stride];
            if ((unsigned)s < (unsigned)n_nodes) {
                int r = atomicAdd(&rank[d - lo], 1);
                int slot = cursor[d] + (int)col_slab[(size_t)chunk * n_nodes + d] + r;
                csr_src[slot] = s;
            }
        }
    }
}

// -------- kernel: y = x @ M, 64x64 tile, 4x4 register micro-tile --------
__global__ __launch_bounds__(256) void mk_y(const float* __restrict__ x,
                                            const float* __restrict__ M,
                                            float* __restrict__ y,
                                            int n_nodes) {
    __shared__ float Ms[IN_CH * OUT_CH];   // 32 KB
    __shared__ float xs[64][IN_CH + 4];
    int tid = threadIdx.x;
    int tx = tid & 15;
    int ty = tid >> 4;
    int row0 = blockIdx.x * 64;

    const float4* Mv = (const float4*)M;
    float4* Msv = (float4*)Ms;
#pragma unroll
    for (int k = 0; k < 8; ++k) Msv[tid + 256 * k] = Mv[tid + 256 * k];

    for (int f = tid; f < 64 * 32; f += 256) {
        int r = f >> 5, kq = f & 31;
        float4 v = make_float4(0.f, 0.f, 0.f, 0.f);
        if (row0 + r < n_nodes)
            v = *(const float4*)&x[(size_t)(row0 + r) * IN_CH + 4 * kq];
        *(float4*)&xs[r][4 * kq] = v;
    }
    __syncthreads();

    float4 acc[4];
#pragma unroll
    for (int j = 0; j < 4; ++j) acc[j] = make_float4(0.f, 0.f, 0.f, 0.f);

    for (int k = 0; k < IN_CH; k += 4) {
        float4 xr[4], mr[4];
#pragma unroll
        for (int j = 0; j < 4; ++j)
            xr[j] = *(const float4*)&xs[4 * ty + j][k];
#pragma unroll
        for (int kk = 0; kk < 4; ++kk)
            mr[kk] = *(const float4*)&Ms[(k + kk) * OUT_CH + 4 * tx];
#pragma unroll
        for (int j = 0; j < 4; ++j) {
            acc[j].x = fmaf(xr[j].x, mr[0].x, acc[j].x);
            acc[j].y = fmaf(xr[j].x, mr[0].y, acc[j].y);
            acc[j].z = fmaf(xr[j].x, mr[0].z, acc[j].z);
            acc[j].w = fmaf(xr[j].x, mr[0].w, acc[j].w);
            acc[j].x = fmaf(xr[j].y, mr[1].x, acc[j].x);
            acc[j].y = fmaf(xr[j].y, mr[1].y, acc[j].y);
            acc[j].z = fmaf(xr[j].y, mr[1].z, acc[j].z);
            acc[j].w = fmaf(xr[j].y, mr[1].w, acc[j].w);
            acc[j].x = fmaf(xr[j].z, mr[2].x, acc[j].x);
            acc[j].y = fmaf(xr[j].z, mr[2].y, acc[j].y);
            acc[j].z = fmaf(xr[j].z, mr[2].z, acc[j].z);
            acc[j].w = fmaf(xr[j].z, mr[2].w, acc[j].w);
            acc[j].x = fmaf(xr[j].w, mr[3].x, acc[j].x);
            acc[j].y = fmaf(xr[j].w, mr[3].y, acc[j].y);
            acc[j].z = fmaf(xr[j].w, mr[3].z, acc[j].z);
            acc[j].w = fmaf(xr[j].w, mr[3].w, acc[j].w);
        }
    }

#pragma unroll
    for (int j = 0; j < 4; ++j) {
        int r = row0 + 4 * ty + j;
        if (r < n_nodes)
            *(float4*)&y[(size_t)r * OUT_CH + 4 * tx] = acc[j];
    }
}

// -------- gather-sum + finalize: one wave per dst node --------
__global__ __launch_bounds__(256) void mk_agg_final(const int* __restrict__ cursor,  // excl starts
                                                    const int* __restrict__ cnt_col,
                                                    const int* __restrict__ csr_src,
                                                    const int* __restrict__ deg_row,
                                                    const float* __restrict__ y,
                                                    const float* __restrict__ c,
                                                    const float* __restrict__ b2,
                                                    float* __restrict__ out,
                                                    int n_nodes) {
    int wave = threadIdx.x >> 6;
    int lane = threadIdx.x & 63;
    int d = blockIdx.x * 4 + wave;
    if (d >= n_nodes) return;
    int start = cursor[d];
    int cnt = cnt_col[d];
    int end = start + cnt;
    float acc = 0.f;
    int j = start;
    for (; j + 3 < end; j += 4) {
        int s0 = csr_src[j];
        int s1 = csr_src[j + 1];
        int s2 = csr_src[j + 2];
        int s3 = csr_src[j + 3];
        float v0 = y[(size_t)s0 * OUT_CH + lane];
        float v1 = y[(size_t)s1 * OUT_CH + lane];
        float v2 = y[(size_t)s2 * OUT_CH + lane];
        float v3 = y[(size_t)s3 * OUT_CH + lane];
        acc += (v0 + v1) + (v2 + v3);
    }
    for (; j < end; ++j)
        acc += y[(size_t)csr_src[j] * OUT_CH + lane];
    int dr = deg_row[d];
    float di = (dr > 0) ? (1.0f / (float)dr) : 0.f;
    out[(size_t)d * OUT_CH + lane] = di * acc + di * (float)cnt * c[lane] + b2[lane];
}

extern "C" void kernel_launch(void* const* d_in, const int* in_sizes, int n_in,
                              void* d_out, int out_size, void* d_ws, size_t ws_size,
                              hipStream_t stream) {
    const float* x  = (const float*)d_in[0];
    const int*   ei = (const int*)d_in[1];
    const float* W1 = (const float*)d_in[2];
    const float* b1 = (const float*)d_in[3];
    const float* W2 = (const float*)d_in[4];
    const float* b2 = (const float*)d_in[5];
    float* out = (float*)d_out;

    const int n_nodes = in_sizes[0] / IN_CH;     // 50000
    const int n_edges = in_sizes[1] / 2;         // 800000

    const size_t slab_bytes = ((size_t)NCHUNK * n_nodes * sizeof(u16) + 127) & ~(size_t)127;

    char* ws = (char*)d_ws;
    float* M        = (float*)(ws);                    // 32768
    float* c        = (float*)(ws + 32768);            // 256
    int*   flag     = (int*)  (ws + 33024);            // 128
    int*   deg_row  = (int*)  (ws + 33152);            // 200064
    int*   cnt_col  = (int*)  (ws + 233216);           // 200064
    int*   cursor   = (int*)  (ws + 433280);           // 200064
    int*   bsums    = (int*)  (ws + 633344);           // 1024
    u16*   row_slab = (u16*)  (ws + 634368);           // 3.2 MB
    u16*   col_slab = (u16*)  (ws + 634368 + slab_bytes);
    int*   csr_src  = (int*)  (ws + 634368 + 2 * slab_bytes);
    float* y        = (float*)(ws + 634368 + 2 * slab_bytes + (size_t)n_edges * 4);

    mk_M_c<<<(IN_CH * OUT_CH + OUT_CH + 1 + 255) / 256, 256, 0, stream>>>(
        W1, b1, W2, ei, M, c, flag);

    mk_y<<<(n_nodes + 63) / 64, 256, 0, stream>>>(x, M, y, n_nodes);

    mk_hist<<<NCHUNK * NRANGE * 2, 256, 0, stream>>>(ei, flag, row_slab, col_slab,
                                                     n_edges, n_nodes);

    mk_chunkoff<<<(n_nodes + 255) / 256, 256, 0, stream>>>(row_slab, col_slab,
                                                           deg_row, cnt_col, n_nodes);

    int nb = (n_nodes + SCAN_B - 1) / SCAN_B;    // 196
    scanA<<<nb, SCAN_B, 0, stream>>>(cnt_col, cursor, bsums, n_nodes);
    scanB<<<1, SCAN_B, 0, stream>>>(bsums, nb);
    scanC<<<nb, SCAN_B, 0, stream>>>(cursor, bsums, n_nodes);

    mk_place<<<NCHUNK * NRANGE, 256, 0, stream>>>(ei, flag, cursor, col_slab,
                                                  csr_src, n_edges, n_nodes);

    mk_agg_final<<<(n_nodes + 3) / 4, 256, 0, stream>>>(cursor, cnt_col, csr_src,
                                                        deg_row, y, c, b2, out, n_nodes);
}

// Round 6
// 194.208 us; speedup vs baseline: 1.6316x; 1.3930x over previous
//
#include <hip/hip_runtime.h>

// SimpleGNN on MI355X — fp32 in/out, edge_index int32/int64 auto-detect.
// out[d] = di[d]*(S[d] @ M) + di[d]*cnt_col[d]*c + b2
//   M = W1^T W2^T [128x64], c = b1 @ W2^T [64]
//   S[d] = sum_{e: col_e=d} x[row_e],  di[d] = 1/deg_row[d] (0 if deg 0)
// Zero global atomics: LDS-privatized histograms + counting-sort CSR build.
// R5 lessons: (1) grid must exceed 2 blocks/CU for latency-bound edge scans;
// (2) never make the second edge-endpoint load conditional on the first —
// batch independent loads so the compiler pipelines vmcnt.

#define IN_CH   128
#define OUT_CH  64
#define SCAN_B  256
#define NCHUNK  64     // edge chunks
#define NRANGE  8      // node ranges
#define RBINS   6272   // bins per range (n_nodes <= 50176), 25 KB per array

typedef unsigned short u16;

// -------- kernel 1: M = W1^T W2^T, c = b1 @ W2^T, + int64-detect flag --------
__global__ __launch_bounds__(256) void mk_M_c(const float* __restrict__ W1,
                                              const float* __restrict__ b1,
                                              const float* __restrict__ W2,
                                              const int* __restrict__ ei,
                                              float* __restrict__ M,   // [128*64]
                                              float* __restrict__ c,   // [64]
                                              int* __restrict__ flag) {
    int tid = blockIdx.x * blockDim.x + threadIdx.x;
    if (tid < IN_CH * OUT_CH) {
        int o = tid & (OUT_CH - 1);
        int i = tid >> 6;
        float acc = 0.f;
        for (int h = 0; h < 128; ++h)
            acc += W1[h * 128 + i] * W2[o * 128 + h];
        M[i * OUT_CH + o] = acc;
    } else if (tid < IN_CH * OUT_CH + OUT_CH) {
        int o = tid - IN_CH * OUT_CH;
        float acc = 0.f;
        for (int h = 0; h < 128; ++h)
            acc += b1[h] * W2[o * 128 + h];
        c[o] = acc;
    } else if (tid == IN_CH * OUT_CH + OUT_CH) {
        // int64 edge_index => odd int32 words all 0 (values < 2^31)
        int f = 1;
        for (int i = 1; i < 64; i += 2)
            if (ei[i] != 0) { f = 0; break; }
        *flag = f;   // 1 = int64 (stride 2), 0 = int32
    }
}

// -------- merged per-(chunk,range) LDS histogram (row AND col) --------
// row bins: count of src values (deg, unconditional).
// col bins: count of dst values where BOTH endpoints valid.
__global__ __launch_bounds__(256) void mk_hist(const int* __restrict__ ei,
                                               const int* __restrict__ flag,
                                               u16* __restrict__ row_slab,  // [NCHUNK][n_nodes]
                                               u16* __restrict__ col_slab,  // [NCHUNK][n_nodes]
                                               int n_edges, int n_nodes) {
    __shared__ int rbins[RBINS];
    __shared__ int cbins[RBINS];
    int b = blockIdx.x;
    int chunk = b & (NCHUNK - 1);
    int range = b >> 6;

    int range_size = (n_nodes + NRANGE - 1) / NRANGE;
    int lo = range * range_size;
    int hi = lo + range_size; if (hi > n_nodes) hi = n_nodes;
    int nbins = hi - lo;
    if (nbins <= 0) return;

    for (int i = threadIdx.x; i < nbins; i += 256) { rbins[i] = 0; cbins[i] = 0; }
    __syncthreads();

    int stride = 1 + *flag;
    size_t e0 = (size_t)chunk * n_edges / NCHUNK;
    size_t e1 = (size_t)(chunk + 1) * n_edges / NCHUNK;
    size_t cnt = e1 - e0;
    const int* rp = ei;                       // row array
    const int* cp = ei + (size_t)n_edges * stride;  // col array

    size_t i = threadIdx.x;
    for (; i + 768 < cnt; i += 1024) {
        // 8 independent loads, then process
        int s0 = rp[(e0 + i) * stride];
        int s1 = rp[(e0 + i + 256) * stride];
        int s2 = rp[(e0 + i + 512) * stride];
        int s3 = rp[(e0 + i + 768) * stride];
        int d0 = cp[(e0 + i) * stride];
        int d1 = cp[(e0 + i + 256) * stride];
        int d2 = cp[(e0 + i + 512) * stride];
        int d3 = cp[(e0 + i + 768) * stride];
        if (s0 >= lo && s0 < hi) atomicAdd(&rbins[s0 - lo], 1);
        if (s1 >= lo && s1 < hi) atomicAdd(&rbins[s1 - lo], 1);
        if (s2 >= lo && s2 < hi) atomicAdd(&rbins[s2 - lo], 1);
        if (s3 >= lo && s3 < hi) atomicAdd(&rbins[s3 - lo], 1);
        if (d0 >= lo && d0 < hi && (unsigned)s0 < (unsigned)n_nodes) atomicAdd(&cbins[d0 - lo], 1);
        if (d1 >= lo && d1 < hi && (unsigned)s1 < (unsigned)n_nodes) atomicAdd(&cbins[d1 - lo], 1);
        if (d2 >= lo && d2 < hi && (unsigned)s2 < (unsigned)n_nodes) atomicAdd(&cbins[d2 - lo], 1);
        if (d3 >= lo && d3 < hi && (unsigned)s3 < (unsigned)n_nodes) atomicAdd(&cbins[d3 - lo], 1);
    }
    for (; i < cnt; i += 256) {
        int s = rp[(e0 + i) * stride];
        int d = cp[(e0 + i) * stride];
        if (s >= lo && s < hi) atomicAdd(&rbins[s - lo], 1);
        if (d >= lo && d < hi && (unsigned)s < (unsigned)n_nodes) atomicAdd(&cbins[d - lo], 1);
    }
    __syncthreads();

    size_t base = (size_t)chunk * n_nodes + lo;
    for (int k = threadIdx.x; k < nbins; k += 256) {
        row_slab[base + k] = (u16)rbins[k];
        col_slab[base + k] = (u16)cbins[k];
    }
}

// -------- fused: per-node slab sums + block-local exclusive scan --------
// deg_row[n], cnt_col[n]; col_slab -> per-chunk exclusive offsets;
// cursor_part[n] = exclusive scan within block; bsums[b] = block total.
__global__ __launch_bounds__(SCAN_B) void mk_choff_scan(u16* __restrict__ row_slab,
                                                        u16* __restrict__ col_slab,
                                                        int* __restrict__ deg_row,
                                                        int* __restrict__ cnt_col,
                                                        int* __restrict__ cursor_part,
                                                        int* __restrict__ bsums,
                                                        int n_nodes) {
    __shared__ int sm[SCAN_B];
    int t = threadIdx.x;
    int n = blockIdx.x * SCAN_B + t;
    int run = 0;
    if (n < n_nodes) {
        int sum = 0;
#pragma unroll
        for (int ch = 0; ch < NCHUNK; ++ch)
            sum += row_slab[(size_t)ch * n_nodes + n];
        deg_row[n] = sum;
#pragma unroll
        for (int ch = 0; ch < NCHUNK; ++ch) {
            int v = col_slab[(size_t)ch * n_nodes + n];
            col_slab[(size_t)ch * n_nodes + n] = (u16)run;
            run += v;
        }
        cnt_col[n] = run;
    }
    sm[t] = run;
    __syncthreads();
    for (int d = 1; d < SCAN_B; d <<= 1) {
        int add = (t >= d) ? sm[t - d] : 0;
        __syncthreads();
        sm[t] += add;
        __syncthreads();
    }
    if (n < n_nodes) cursor_part[n] = sm[t] - run;
    if (t == SCAN_B - 1) bsums[blockIdx.x] = sm[t];
}

// -------- scan of block sums (nb <= 1024) --------
__global__ __launch_bounds__(1024) void scanB(int* __restrict__ bsums, int nb) {
    __shared__ int s[1024];
    int t = threadIdx.x;
    int v = (t < nb) ? bsums[t] : 0;
    s[t] = v;
    __syncthreads();
    for (int d = 1; d < 1024; d <<= 1) {
        int add = (t >= d) ? s[t - d] : 0;
        __syncthreads();
        s[t] += add;
        __syncthreads();
    }
    if (t < nb) bsums[t] = s[t] - v;
}

// -------- counting-sort placement: plain stores, no global atomics --------
__global__ __launch_bounds__(256) void mk_place(const int* __restrict__ ei,
                                                const int* __restrict__ flag,
                                                const int* __restrict__ cursor_part,
                                                const int* __restrict__ bsums,
                                                const u16* __restrict__ col_slab,
                                                int* __restrict__ csr_src,
                                                int n_edges, int n_nodes) {
    __shared__ int rank[RBINS];
    int b = blockIdx.x;
    int chunk = b & (NCHUNK - 1);
    int range = b >> 6;

    int range_size = (n_nodes + NRANGE - 1) / NRANGE;
    int lo = range * range_size;
    int hi = lo + range_size; if (hi > n_nodes) hi = n_nodes;
    if (hi <= lo) return;

    for (int i = threadIdx.x; i < hi - lo; i += 256) rank[i] = 0;
    __syncthreads();

    int stride = 1 + *flag;
    size_t e0 = (size_t)chunk * n_edges / NCHUNK;
    size_t e1 = (size_t)(chunk + 1) * n_edges / NCHUNK;
    size_t cnt = e1 - e0;
    const int* rp = ei;
    const int* cp = ei + (size_t)n_edges * stride;
    size_t slab_base = (size_t)chunk * n_nodes;

    size_t i = threadIdx.x;
    for (; i + 768 < cnt; i += 1024) {
        int s0 = rp[(e0 + i) * stride];
        int s1 = rp[(e0 + i + 256) * stride];
        int s2 = rp[(e0 + i + 512) * stride];
        int s3 = rp[(e0 + i + 768) * stride];
        int d0 = cp[(e0 + i) * stride];
        int d1 = cp[(e0 + i + 256) * stride];
        int d2 = cp[(e0 + i + 512) * stride];
        int d3 = cp[(e0 + i + 768) * stride];
        if (d0 >= lo && d0 < hi && (unsigned)s0 < (unsigned)n_nodes) {
            int r = atomicAdd(&rank[d0 - lo], 1);
            csr_src[cursor_part[d0] + bsums[d0 >> 8] + (int)col_slab[slab_base + d0] + r] = s0;
        }
        if (d1 >= lo && d1 < hi && (unsigned)s1 < (unsigned)n_nodes) {
            int r = atomicAdd(&rank[d1 - lo], 1);
            csr_src[cursor_part[d1] + bsums[d1 >> 8] + (int)col_slab[slab_base + d1] + r] = s1;
        }
        if (d2 >= lo && d2 < hi && (unsigned)s2 < (unsigned)n_nodes) {
            int r = atomicAdd(&rank[d2 - lo], 1);
            csr_src[cursor_part[d2] + bsums[d2 >> 8] + (int)col_slab[slab_base + d2] + r] = s2;
        }
        if (d3 >= lo && d3 < hi && (unsigned)s3 < (unsigned)n_nodes) {
            int r = atomicAdd(&rank[d3 - lo], 1);
            csr_src[cursor_part[d3] + bsums[d3 >> 8] + (int)col_slab[slab_base + d3] + r] = s3;
        }
    }
    for (; i < cnt; i += 256) {
        int s = rp[(e0 + i) * stride];
        int d = cp[(e0 + i) * stride];
        if (d >= lo && d < hi && (unsigned)s < (unsigned)n_nodes) {
            int r = atomicAdd(&rank[d - lo], 1);
            csr_src[cursor_part[d] + bsums[d >> 8] + (int)col_slab[slab_base + d] + r] = s;
        }
    }
}

// -------- kernel: y = x @ M, 64x64 tile, 4x4 register micro-tile --------
__global__ __launch_bounds__(256) void mk_y(const float* __restrict__ x,
                                            const float* __restrict__ M,
                                            float* __restrict__ y,
                                            int n_nodes) {
    __shared__ float Ms[IN_CH * OUT_CH];   // 32 KB
    __shared__ float xs[64][IN_CH + 4];
    int tid = threadIdx.x;
    int tx = tid & 15;
    int ty = tid >> 4;
    int row0 = blockIdx.x * 64;

    const float4* Mv = (const float4*)M;
    float4* Msv = (float4*)Ms;
#pragma unroll
    for (int k = 0; k < 8; ++k) Msv[tid + 256 * k] = Mv[tid + 256 * k];

    for (int f = tid; f < 64 * 32; f += 256) {
        int r = f >> 5, kq = f & 31;
        float4 v = make_float4(0.f, 0.f, 0.f, 0.f);
        if (row0 + r < n_nodes)
            v = *(const float4*)&x[(size_t)(row0 + r) * IN_CH + 4 * kq];
        *(float4*)&xs[r][4 * kq] = v;
    }
    __syncthreads();

    float4 acc[4];
#pragma unroll
    for (int j = 0; j < 4; ++j) acc[j] = make_float4(0.f, 0.f, 0.f, 0.f);

    for (int k = 0; k < IN_CH; k += 4) {
        float4 xr[4], mr[4];
#pragma unroll
        for (int j = 0; j < 4; ++j)
            xr[j] = *(const float4*)&xs[4 * ty + j][k];
#pragma unroll
        for (int kk = 0; kk < 4; ++kk)
            mr[kk] = *(const float4*)&Ms[(k + kk) * OUT_CH + 4 * tx];
#pragma unroll
        for (int j = 0; j < 4; ++j) {
            acc[j].x = fmaf(xr[j].x, mr[0].x, acc[j].x);
            acc[j].y = fmaf(xr[j].x, mr[0].y, acc[j].y);
            acc[j].z = fmaf(xr[j].x, mr[0].z, acc[j].z);
            acc[j].w = fmaf(xr[j].x, mr[0].w, acc[j].w);
            acc[j].x = fmaf(xr[j].y, mr[1].x, acc[j].x);
            acc[j].y = fmaf(xr[j].y, mr[1].y, acc[j].y);
            acc[j].z = fmaf(xr[j].y, mr[1].z, acc[j].z);
            acc[j].w = fmaf(xr[j].y, mr[1].w, acc[j].w);
            acc[j].x = fmaf(xr[j].z, mr[2].x, acc[j].x);
            acc[j].y = fmaf(xr[j].z, mr[2].y, acc[j].y);
            acc[j].z = fmaf(xr[j].z, mr[2].z, acc[j].z);
            acc[j].w = fmaf(xr[j].z, mr[2].w, acc[j].w);
            acc[j].x = fmaf(xr[j].w, mr[3].x, acc[j].x);
            acc[j].y = fmaf(xr[j].w, mr[3].y, acc[j].y);
            acc[j].z = fmaf(xr[j].w, mr[3].z, acc[j].z);
            acc[j].w = fmaf(xr[j].w, mr[3].w, acc[j].w);
        }
    }

#pragma unroll
    for (int j = 0; j < 4; ++j) {
        int r = row0 + 4 * ty + j;
        if (r < n_nodes)
            *(float4*)&y[(size_t)r * OUT_CH + 4 * tx] = acc[j];
    }
}

// -------- gather-sum + finalize: one wave per dst node --------
__global__ __launch_bounds__(256) void mk_agg_final(const int* __restrict__ cursor_part,
                                                    const int* __restrict__ bsums,
                                                    const int* __restrict__ cnt_col,
                                                    const int* __restrict__ csr_src,
                                                    const int* __restrict__ deg_row,
                                                    const float* __restrict__ y,
                                                    const float* __restrict__ c,
                                                    const float* __restrict__ b2,
                                                    float* __restrict__ out,
                                                    int n_nodes) {
    int wave = threadIdx.x >> 6;
    int lane = threadIdx.x & 63;
    int d = blockIdx.x * 4 + wave;
    if (d >= n_nodes) return;
    int start = cursor_part[d] + bsums[d >> 8];
    int cnt = cnt_col[d];
    int end = start + cnt;
    float acc = 0.f;
    int j = start;
    for (; j + 7 < end; j += 8) {
        int s0 = csr_src[j];
        int s1 = csr_src[j + 1];
        int s2 = csr_src[j + 2];
        int s3 = csr_src[j + 3];
        int s4 = csr_src[j + 4];
        int s5 = csr_src[j + 5];
        int s6 = csr_src[j + 6];
        int s7 = csr_src[j + 7];
        float v0 = y[(size_t)s0 * OUT_CH + lane];
        float v1 = y[(size_t)s1 * OUT_CH + lane];
        float v2 = y[(size_t)s2 * OUT_CH + lane];
        float v3 = y[(size_t)s3 * OUT_CH + lane];
        float v4 = y[(size_t)s4 * OUT_CH + lane];
        float v5 = y[(size_t)s5 * OUT_CH + lane];
        float v6 = y[(size_t)s6 * OUT_CH + lane];
        float v7 = y[(size_t)s7 * OUT_CH + lane];
        acc += ((v0 + v1) + (v2 + v3)) + ((v4 + v5) + (v6 + v7));
    }
    for (; j < end; ++j)
        acc += y[(size_t)csr_src[j] * OUT_CH + lane];
    int dr = deg_row[d];
    float di = (dr > 0) ? (1.0f / (float)dr) : 0.f;
    out[(size_t)d * OUT_CH + lane] = di * acc + di * (float)cnt * c[lane] + b2[lane];
}

extern "C" void kernel_launch(void* const* d_in, const int* in_sizes, int n_in,
                              void* d_out, int out_size, void* d_ws, size_t ws_size,
                              hipStream_t stream) {
    const float* x  = (const float*)d_in[0];
    const int*   ei = (const int*)d_in[1];
    const float* W1 = (const float*)d_in[2];
    const float* b1 = (const float*)d_in[3];
    const float* W2 = (const float*)d_in[4];
    const float* b2 = (const float*)d_in[5];
    float* out = (float*)d_out;

    const int n_nodes = in_sizes[0] / IN_CH;     // 50000
    const int n_edges = in_sizes[1] / 2;         // 800000

    const size_t slab_bytes = ((size_t)NCHUNK * n_nodes * sizeof(u16) + 127) & ~(size_t)127;

    char* ws = (char*)d_ws;
    float* M        = (float*)(ws);                    // 32768
    float* c        = (float*)(ws + 32768);            // 256
    int*   flag     = (int*)  (ws + 33024);            // 128
    int*   deg_row  = (int*)  (ws + 33152);            // 200064
    int*   cnt_col  = (int*)  (ws + 233216);           // 200064
    int*   cursor   = (int*)  (ws + 433280);           // 200064 (cursor_part)
    int*   bsums    = (int*)  (ws + 633344);           // 4096
    u16*   row_slab = (u16*)  (ws + 637440);           // 6.4 MB
    u16*   col_slab = (u16*)  (ws + 637440 + slab_bytes);
    int*   csr_src  = (int*)  (ws + 637440 + 2 * slab_bytes);
    float* y        = (float*)(ws + 637440 + 2 * slab_bytes + (size_t)n_edges * 4);

    mk_M_c<<<(IN_CH * OUT_CH + OUT_CH + 1 + 255) / 256, 256, 0, stream>>>(
        W1, b1, W2, ei, M, c, flag);

    mk_y<<<(n_nodes + 63) / 64, 256, 0, stream>>>(x, M, y, n_nodes);

    mk_hist<<<NCHUNK * NRANGE, 256, 0, stream>>>(ei, flag, row_slab, col_slab,
                                                 n_edges, n_nodes);

    int nb = (n_nodes + SCAN_B - 1) / SCAN_B;    // 196
    mk_choff_scan<<<nb, SCAN_B, 0, stream>>>(row_slab, col_slab, deg_row, cnt_col,
                                             cursor, bsums, n_nodes);
    scanB<<<1, 1024, 0, stream>>>(bsums, nb);

    mk_place<<<NCHUNK * NRANGE, 256, 0, stream>>>(ei, flag, cursor, bsums, col_slab,
                                                  csr_src, n_edges, n_nodes);

    mk_agg_final<<<(n_nodes + 3) / 4, 256, 0, stream>>>(cursor, bsums, cnt_col, csr_src,
                                                        deg_row, y, c, b2, out, n_nodes);
}

// Round 7
// 193.279 us; speedup vs baseline: 1.6395x; 1.0048x over previous
//
#include <hip/hip_runtime.h>
#include <hip/hip_bf16.h>

// SimpleGNN on MI355X — fp32 in/out, edge_index int32/int64 auto-detect.
// out[d] = di[d]*(S[d] @ M) + di[d]*cnt_col[d]*c + b2
//   M = W1^T W2^T [128x64], c = b1 @ W2^T [64]
//   S[d] = sum_{e: col_e=d} x[row_e],  di[d] = 1/deg_row[d] (0 if deg 0)
// Zero global atomics; y stored bf16 (gather row = one 128B line).
// R5/R6 lessons: >=4 blocks/CU for edge scans; batch independent loads;
// no serial latency tails (masked batches).

#define IN_CH   128
#define OUT_CH  64
#define SCAN_B  256
#define NRANGE  8
#define RBINS   6272   // bins per range (n_nodes <= 50176)

typedef unsigned short u16;

static __device__ inline u16 f2bf(float f) {
    __hip_bfloat16 h = __float2bfloat16(f);
    return *reinterpret_cast<u16*>(&h);
}
static __device__ inline float bf2f(u16 u) {
    __hip_bfloat16 h = *reinterpret_cast<__hip_bfloat16*>(&u);
    return __bfloat162float(h);
}

// -------- kernel 1: M = W1^T W2^T, c = b1 @ W2^T, + int64-detect flag --------
__global__ __launch_bounds__(256) void mk_M_c(const float* __restrict__ W1,
                                              const float* __restrict__ b1,
                                              const float* __restrict__ W2,
                                              const int* __restrict__ ei,
                                              float* __restrict__ M,   // [128*64]
                                              float* __restrict__ c,   // [64]
                                              int* __restrict__ flag) {
    int tid = blockIdx.x * blockDim.x + threadIdx.x;
    if (tid < IN_CH * OUT_CH) {
        int o = tid & (OUT_CH - 1);
        int i = tid >> 6;
        float acc = 0.f;
        for (int h = 0; h < 128; ++h)
            acc += W1[h * 128 + i] * W2[o * 128 + h];
        M[i * OUT_CH + o] = acc;
    } else if (tid < IN_CH * OUT_CH + OUT_CH) {
        int o = tid - IN_CH * OUT_CH;
        float acc = 0.f;
        for (int h = 0; h < 128; ++h)
            acc += b1[h] * W2[o * 128 + h];
        c[o] = acc;
    } else if (tid == IN_CH * OUT_CH + OUT_CH) {
        int f = 1;
        for (int i = 1; i < 64; i += 2)
            if (ei[i] != 0) { f = 0; break; }
        *flag = f;   // 1 = int64 (stride 2), 0 = int32
    }
}

// -------- per-(chunk,range) packed LDS histogram: row in lo16, col in hi16 --------
__global__ __launch_bounds__(256) void mk_hist(const int* __restrict__ ei,
                                               const int* __restrict__ flag,
                                               u16* __restrict__ row_slab,  // [nchunk][n_nodes]
                                               u16* __restrict__ col_slab,  // [nchunk][n_nodes]
                                               int n_edges, int n_nodes,
                                               int nchunk, int lg) {
    __shared__ unsigned int bins[RBINS];
    int b = blockIdx.x;
    int chunk = b & (nchunk - 1);
    int range = b >> lg;

    int range_size = (n_nodes + NRANGE - 1) / NRANGE;
    int lo = range * range_size;
    int hi = lo + range_size; if (hi > n_nodes) hi = n_nodes;
    int nbins = hi - lo;
    if (nbins <= 0) return;

    for (int i = threadIdx.x; i < nbins; i += 256) bins[i] = 0u;
    __syncthreads();

    int stride = 1 + *flag;
    size_t e0 = (size_t)chunk * n_edges / nchunk;
    size_t e1 = (size_t)(chunk + 1) * n_edges / nchunk;
    size_t cnt = e1 - e0;
    const int* rp = ei;
    const int* cp = ei + (size_t)n_edges * stride;

    size_t i = threadIdx.x;
    for (; i + 768 < cnt; i += 1024) {
        int s0 = rp[(e0 + i) * stride];
        int s1 = rp[(e0 + i + 256) * stride];
        int s2 = rp[(e0 + i + 512) * stride];
        int s3 = rp[(e0 + i + 768) * stride];
        int d0 = cp[(e0 + i) * stride];
        int d1 = cp[(e0 + i + 256) * stride];
        int d2 = cp[(e0 + i + 512) * stride];
        int d3 = cp[(e0 + i + 768) * stride];
        if (s0 >= lo && s0 < hi) atomicAdd(&bins[s0 - lo], 1u);
        if (s1 >= lo && s1 < hi) atomicAdd(&bins[s1 - lo], 1u);
        if (s2 >= lo && s2 < hi) atomicAdd(&bins[s2 - lo], 1u);
        if (s3 >= lo && s3 < hi) atomicAdd(&bins[s3 - lo], 1u);
        if (d0 >= lo && d0 < hi && (unsigned)s0 < (unsigned)n_nodes) atomicAdd(&bins[d0 - lo], 0x10000u);
        if (d1 >= lo && d1 < hi && (unsigned)s1 < (unsigned)n_nodes) atomicAdd(&bins[d1 - lo], 0x10000u);
        if (d2 >= lo && d2 < hi && (unsigned)s2 < (unsigned)n_nodes) atomicAdd(&bins[d2 - lo], 0x10000u);
        if (d3 >= lo && d3 < hi && (unsigned)s3 < (unsigned)n_nodes) atomicAdd(&bins[d3 - lo], 0x10000u);
    }
    for (; i < cnt; i += 256) {
        int s = rp[(e0 + i) * stride];
        int d = cp[(e0 + i) * stride];
        if (s >= lo && s < hi) atomicAdd(&bins[s - lo], 1u);
        if (d >= lo && d < hi && (unsigned)s < (unsigned)n_nodes) atomicAdd(&bins[d - lo], 0x10000u);
    }
    __syncthreads();

    size_t base = (size_t)chunk * n_nodes + lo;
    for (int k = threadIdx.x; k < nbins; k += 256) {
        unsigned int v = bins[k];
        row_slab[base + k] = (u16)(v & 0xFFFFu);
        col_slab[base + k] = (u16)(v >> 16);
    }
}

// -------- fused: per-node slab sums + block-local exclusive scan --------
__global__ __launch_bounds__(SCAN_B) void mk_choff_scan(u16* __restrict__ row_slab,
                                                        u16* __restrict__ col_slab,
                                                        int* __restrict__ deg_row,
                                                        int* __restrict__ cnt_col,
                                                        int* __restrict__ cursor_part,
                                                        int* __restrict__ bsums,
                                                        int n_nodes, int nchunk) {
    __shared__ int sm[SCAN_B];
    int t = threadIdx.x;
    int n = blockIdx.x * SCAN_B + t;
    int run = 0;
    if (n < n_nodes) {
        int sum = 0;
#pragma unroll 8
        for (int ch = 0; ch < nchunk; ++ch)
            sum += row_slab[(size_t)ch * n_nodes + n];
        deg_row[n] = sum;
#pragma unroll 8
        for (int ch = 0; ch < nchunk; ++ch) {
            int v = col_slab[(size_t)ch * n_nodes + n];
            col_slab[(size_t)ch * n_nodes + n] = (u16)run;
            run += v;
        }
        cnt_col[n] = run;
    }
    sm[t] = run;
    __syncthreads();
    for (int d = 1; d < SCAN_B; d <<= 1) {
        int add = (t >= d) ? sm[t - d] : 0;
        __syncthreads();
        sm[t] += add;
        __syncthreads();
    }
    if (n < n_nodes) cursor_part[n] = sm[t] - run;
    if (t == SCAN_B - 1) bsums[blockIdx.x] = sm[t];
}

// -------- scan of block sums (nb <= 1024) --------
__global__ __launch_bounds__(1024) void scanB(int* __restrict__ bsums, int nb) {
    __shared__ int s[1024];
    int t = threadIdx.x;
    int v = (t < nb) ? bsums[t] : 0;
    s[t] = v;
    __syncthreads();
    for (int d = 1; d < 1024; d <<= 1) {
        int add = (t >= d) ? s[t - d] : 0;
        __syncthreads();
        s[t] += add;
        __syncthreads();
    }
    if (t < nb) bsums[t] = s[t] - v;
}

// -------- counting-sort placement: plain stores, no global atomics --------
__global__ __launch_bounds__(256) void mk_place(const int* __restrict__ ei,
                                                const int* __restrict__ flag,
                                                const int* __restrict__ cursor_part,
                                                const int* __restrict__ bsums,
                                                const u16* __restrict__ col_slab,
                                                int* __restrict__ csr_src,
                                                int n_edges, int n_nodes,
                                                int nchunk, int lg) {
    __shared__ int rank[RBINS];
    int b = blockIdx.x;
    int chunk = b & (nchunk - 1);
    int range = b >> lg;

    int range_size = (n_nodes + NRANGE - 1) / NRANGE;
    int lo = range * range_size;
    int hi = lo + range_size; if (hi > n_nodes) hi = n_nodes;
    if (hi <= lo) return;

    for (int i = threadIdx.x; i < hi - lo; i += 256) rank[i] = 0;
    __syncthreads();

    int stride = 1 + *flag;
    size_t e0 = (size_t)chunk * n_edges / nchunk;
    size_t e1 = (size_t)(chunk + 1) * n_edges / nchunk;
    size_t cnt = e1 - e0;
    const int* rp = ei;
    const int* cp = ei + (size_t)n_edges * stride;
    size_t slab_base = (size_t)chunk * n_nodes;

    size_t i = threadIdx.x;
    for (; i + 768 < cnt; i += 1024) {
        int s0 = rp[(e0 + i) * stride];
        int s1 = rp[(e0 + i + 256) * stride];
        int s2 = rp[(e0 + i + 512) * stride];
        int s3 = rp[(e0 + i + 768) * stride];
        int d0 = cp[(e0 + i) * stride];
        int d1 = cp[(e0 + i + 256) * stride];
        int d2 = cp[(e0 + i + 512) * stride];
        int d3 = cp[(e0 + i + 768) * stride];
        if (d0 >= lo && d0 < hi && (unsigned)s0 < (unsigned)n_nodes) {
            int r = atomicAdd(&rank[d0 - lo], 1);
            csr_src[cursor_part[d0] + bsums[d0 >> 8] + (int)col_slab[slab_base + d0] + r] = s0;
        }
        if (d1 >= lo && d1 < hi && (unsigned)s1 < (unsigned)n_nodes) {
            int r = atomicAdd(&rank[d1 - lo], 1);
            csr_src[cursor_part[d1] + bsums[d1 >> 8] + (int)col_slab[slab_base + d1] + r] = s1;
        }
        if (d2 >= lo && d2 < hi && (unsigned)s2 < (unsigned)n_nodes) {
            int r = atomicAdd(&rank[d2 - lo], 1);
            csr_src[cursor_part[d2] + bsums[d2 >> 8] + (int)col_slab[slab_base + d2] + r] = s2;
        }
        if (d3 >= lo && d3 < hi && (unsigned)s3 < (unsigned)n_nodes) {
            int r = atomicAdd(&rank[d3 - lo], 1);
            csr_src[cursor_part[d3] + bsums[d3 >> 8] + (int)col_slab[slab_base + d3] + r] = s3;
        }
    }
    for (; i < cnt; i += 256) {
        int s = rp[(e0 + i) * stride];
        int d = cp[(e0 + i) * stride];
        if (d >= lo && d < hi && (unsigned)s < (unsigned)n_nodes) {
            int r = atomicAdd(&rank[d - lo], 1);
            csr_src[cursor_part[d] + bsums[d >> 8] + (int)col_slab[slab_base + d] + r] = s;
        }
    }
}

// -------- kernel: y = x @ M (fp32 compute, bf16 store) --------
__global__ __launch_bounds__(256) void mk_y(const float* __restrict__ x,
                                            const float* __restrict__ M,
                                            u16* __restrict__ y,
                                            int n_nodes) {
    __shared__ float Ms[IN_CH * OUT_CH];   // 32 KB
    __shared__ float xs[64][IN_CH + 4];
    int tid = threadIdx.x;
    int tx = tid & 15;
    int ty = tid >> 4;
    int row0 = blockIdx.x * 64;

    const float4* Mv = (const float4*)M;
    float4* Msv = (float4*)Ms;
#pragma unroll
    for (int k = 0; k < 8; ++k) Msv[tid + 256 * k] = Mv[tid + 256 * k];

    for (int f = tid; f < 64 * 32; f += 256) {
        int r = f >> 5, kq = f & 31;
        float4 v = make_float4(0.f, 0.f, 0.f, 0.f);
        if (row0 + r < n_nodes)
            v = *(const float4*)&x[(size_t)(row0 + r) * IN_CH + 4 * kq];
        *(float4*)&xs[r][4 * kq] = v;
    }
    __syncthreads();

    float4 acc[4];
#pragma unroll
    for (int j = 0; j < 4; ++j) acc[j] = make_float4(0.f, 0.f, 0.f, 0.f);

    for (int k = 0; k < IN_CH; k += 4) {
        float4 xr[4], mr[4];
#pragma unroll
        for (int j = 0; j < 4; ++j)
            xr[j] = *(const float4*)&xs[4 * ty + j][k];
#pragma unroll
        for (int kk = 0; kk < 4; ++kk)
            mr[kk] = *(const float4*)&Ms[(k + kk) * OUT_CH + 4 * tx];
#pragma unroll
        for (int j = 0; j < 4; ++j) {
            acc[j].x = fmaf(xr[j].x, mr[0].x, acc[j].x);
            acc[j].y = fmaf(xr[j].x, mr[0].y, acc[j].y);
            acc[j].z = fmaf(xr[j].x, mr[0].z, acc[j].z);
            acc[j].w = fmaf(xr[j].x, mr[0].w, acc[j].w);
            acc[j].x = fmaf(xr[j].y, mr[1].x, acc[j].x);
            acc[j].y = fmaf(xr[j].y, mr[1].y, acc[j].y);
            acc[j].z = fmaf(xr[j].y, mr[1].z, acc[j].z);
            acc[j].w = fmaf(xr[j].y, mr[1].w, acc[j].w);
            acc[j].x = fmaf(xr[j].z, mr[2].x, acc[j].x);
            acc[j].y = fmaf(xr[j].z, mr[2].y, acc[j].y);
            acc[j].z = fmaf(xr[j].z, mr[2].z, acc[j].z);
            acc[j].w = fmaf(xr[j].z, mr[2].w, acc[j].w);
            acc[j].x = fmaf(xr[j].w, mr[3].x, acc[j].x);
            acc[j].y = fmaf(xr[j].w, mr[3].y, acc[j].y);
            acc[j].z = fmaf(xr[j].w, mr[3].z, acc[j].z);
            acc[j].w = fmaf(xr[j].w, mr[3].w, acc[j].w);
        }
    }

#pragma unroll
    for (int j = 0; j < 4; ++j) {
        int r = row0 + 4 * ty + j;
        if (r < n_nodes) {
            ushort4 s4;
            s4.x = f2bf(acc[j].x);
            s4.y = f2bf(acc[j].y);
            s4.z = f2bf(acc[j].z);
            s4.w = f2bf(acc[j].w);
            *(ushort4*)&y[(size_t)r * OUT_CH + 4 * tx] = s4;
        }
    }
}

// -------- gather-sum + finalize: one wave per dst, masked batches of 8 --------
__global__ __launch_bounds__(256) void mk_agg_final(const int* __restrict__ cursor_part,
                                                    const int* __restrict__ bsums,
                                                    const int* __restrict__ cnt_col,
                                                    const int* __restrict__ csr_src,
                                                    const int* __restrict__ deg_row,
                                                    const u16* __restrict__ y,
                                                    const float* __restrict__ c,
                                                    const float* __restrict__ b2,
                                                    float* __restrict__ out,
                                                    int n_nodes) {
    int wave = threadIdx.x >> 6;
    int lane = threadIdx.x & 63;
    int d = blockIdx.x * 4 + wave;
    if (d >= n_nodes) return;
    int start = cursor_part[d] + bsums[d >> 8];
    int cnt = cnt_col[d];
    int end = start + cnt;
    float acc = 0.f;
    int e1m = end - 1;
    for (int j = start; j < end; j += 8) {
        int i1 = j + 1 > e1m ? e1m : j + 1;
        int i2 = j + 2 > e1m ? e1m : j + 2;
        int i3 = j + 3 > e1m ? e1m : j + 3;
        int i4 = j + 4 > e1m ? e1m : j + 4;
        int i5 = j + 5 > e1m ? e1m : j + 5;
        int i6 = j + 6 > e1m ? e1m : j + 6;
        int i7 = j + 7 > e1m ? e1m : j + 7;
        int s0 = csr_src[j];
        int s1 = csr_src[i1];
        int s2 = csr_src[i2];
        int s3 = csr_src[i3];
        int s4 = csr_src[i4];
        int s5 = csr_src[i5];
        int s6 = csr_src[i6];
        int s7 = csr_src[i7];
        float v0 = bf2f(y[(size_t)s0 * OUT_CH + lane]);
        float v1 = bf2f(y[(size_t)s1 * OUT_CH + lane]);
        float v2 = bf2f(y[(size_t)s2 * OUT_CH + lane]);
        float v3 = bf2f(y[(size_t)s3 * OUT_CH + lane]);
        float v4 = bf2f(y[(size_t)s4 * OUT_CH + lane]);
        float v5 = bf2f(y[(size_t)s5 * OUT_CH + lane]);
        float v6 = bf2f(y[(size_t)s6 * OUT_CH + lane]);
        float v7 = bf2f(y[(size_t)s7 * OUT_CH + lane]);
        v1 = (j + 1 < end) ? v1 : 0.f;
        v2 = (j + 2 < end) ? v2 : 0.f;
        v3 = (j + 3 < end) ? v3 : 0.f;
        v4 = (j + 4 < end) ? v4 : 0.f;
        v5 = (j + 5 < end) ? v5 : 0.f;
        v6 = (j + 6 < end) ? v6 : 0.f;
        v7 = (j + 7 < end) ? v7 : 0.f;
        acc += ((v0 + v1) + (v2 + v3)) + ((v4 + v5) + (v6 + v7));
    }
    int dr = deg_row[d];
    float di = (dr > 0) ? (1.0f / (float)dr) : 0.f;
    out[(size_t)d * OUT_CH + lane] = di * acc + di * (float)cnt * c[lane] + b2[lane];
}

extern "C" void kernel_launch(void* const* d_in, const int* in_sizes, int n_in,
                              void* d_out, int out_size, void* d_ws, size_t ws_size,
                              hipStream_t stream) {
    const float* x  = (const float*)d_in[0];
    const int*   ei = (const int*)d_in[1];
    const float* W1 = (const float*)d_in[2];
    const float* b1 = (const float*)d_in[3];
    const float* W2 = (const float*)d_in[4];
    const float* b2 = (const float*)d_in[5];
    float* out = (float*)d_out;

    const int n_nodes = in_sizes[0] / IN_CH;     // 50000
    const int n_edges = in_sizes[1] / 2;         // 800000

    // choose nchunk: 128 if workspace allows, else 64
    const size_t base = 637440;
    const size_t csr_bytes = ((size_t)n_edges * 4 + 127) & ~(size_t)127;
    const size_t y_bytes = ((size_t)n_nodes * OUT_CH * 2 + 127) & ~(size_t)127;
    int nchunk = 128, lg = 7;
    {
        size_t slab = (((size_t)nchunk * n_nodes * 2) + 127) & ~(size_t)127;
        if (base + 2 * slab + csr_bytes + y_bytes > ws_size) { nchunk = 64; lg = 6; }
    }
    const size_t slab_bytes = (((size_t)nchunk * n_nodes * 2) + 127) & ~(size_t)127;

    char* ws = (char*)d_ws;
    float* M        = (float*)(ws);                    // 32768
    float* c        = (float*)(ws + 32768);            // 256
    int*   flag     = (int*)  (ws + 33024);            // 128
    int*   deg_row  = (int*)  (ws + 33152);            // 200064
    int*   cnt_col  = (int*)  (ws + 233216);           // 200064
    int*   cursor   = (int*)  (ws + 433280);           // 200064 (cursor_part)
    int*   bsums    = (int*)  (ws + 633344);           // 4096
    u16*   row_slab = (u16*)  (ws + base);
    u16*   col_slab = (u16*)  (ws + base + slab_bytes);
    int*   csr_src  = (int*)  (ws + base + 2 * slab_bytes);
    u16*   y        = (u16*)  (ws + base + 2 * slab_bytes + csr_bytes);

    mk_M_c<<<(IN_CH * OUT_CH + OUT_CH + 1 + 255) / 256, 256, 0, stream>>>(
        W1, b1, W2, ei, M, c, flag);

    mk_y<<<(n_nodes + 63) / 64, 256, 0, stream>>>(x, M, y, n_nodes);

    mk_hist<<<nchunk * NRANGE, 256, 0, stream>>>(ei, flag, row_slab, col_slab,
                                                 n_edges, n_nodes, nchunk, lg);

    int nb = (n_nodes + SCAN_B - 1) / SCAN_B;    // 196
    mk_choff_scan<<<nb, SCAN_B, 0, stream>>>(row_slab, col_slab, deg_row, cnt_col,
                                             cursor, bsums, n_nodes, nchunk);
    scanB<<<1, 1024, 0, stream>>>(bsums, nb);

    mk_place<<<nchunk * NRANGE, 256, 0, stream>>>(ei, flag, cursor, bsums, col_slab,
                                                  csr_src, n_edges, n_nodes, nchunk, lg);

    mk_agg_final<<<(n_nodes + 3) / 4, 256, 0, stream>>>(cursor, bsums, cnt_col, csr_src,
                                                        deg_row, y, c, b2, out, n_nodes);
}

// Round 8
// 162.068 us; speedup vs baseline: 1.9552x; 1.1926x over previous
//
#include <hip/hip_runtime.h>
#include <hip/hip_bf16.h>

// SimpleGNN on MI355X — fp32 in/out, edge_index int32/int64 auto-detect.
// out[d] = di[d]*(S[d] @ M) + di[d]*cnt_col[d]*c + b2
//   M = W1^T W2^T [128x64], c = b1 @ W2^T [64]
//   S[d] = sum_{e: col_e=d} x[row_e],  di[d] = 1/deg_row[d] (0 if deg 0)
// Zero global atomics; y bf16; 4 fused dispatches:
//   K1 [M_c | hist]   K2 [y | choff_scan]   K3 place   K4 agg_final
// R7 lesson: time was flat across 8 small dispatches — cut launch count,
// co-schedule latency-bound and compute-bound blocks in one grid.

#define IN_CH   128
#define OUT_CH  64
#define NCHUNK  64
#define LGCHUNK 6
#define NRANGE  8
#define RBINS   6272   // ceil(50176/8); 25 KB LDS
#define MC_BLOCKS 33   // ceil((128*64+64)/256)

typedef unsigned short u16;
typedef unsigned int u32;

static __device__ inline float bfu32_lo(u32 u) {
    u32 v = u << 16; return __uint_as_float(v);
}
static __device__ inline float bfu32_hi(u32 u) {
    u32 v = u & 0xffff0000u; return __uint_as_float(v);
}
static __device__ inline u16 f2bf(float f) {
    __hip_bfloat16 h = __float2bfloat16(f);
    return *reinterpret_cast<u16*>(&h);
}

// stride detect: int64 edge_index => odd int32 words all 0 (values < 2^31)
static __device__ inline int detect_stride(const int* ei) {
    int f = 1;
    for (int i = 1; i < 64; i += 2)
        if (ei[i] != 0) { f = 0; break; }
    return 1 + f;
}

// ================= K1: [M_c | hist] =================
__global__ __launch_bounds__(256) void mk_prep(const float* __restrict__ W1,
                                               const float* __restrict__ b1,
                                               const float* __restrict__ W2,
                                               const int* __restrict__ ei,
                                               float* __restrict__ M,
                                               float* __restrict__ c,
                                               u16* __restrict__ row_slab,
                                               u16* __restrict__ col_slab,
                                               int n_edges, int n_nodes) {
    __shared__ u32 bins[RBINS];
    __shared__ int s_stride;
    int b = blockIdx.x;
    if (b < MC_BLOCKS) {
        int tid = b * 256 + threadIdx.x;
        if (tid < IN_CH * OUT_CH) {
            int o = tid & (OUT_CH - 1);
            int i = tid >> 6;
            float acc = 0.f;
            for (int h = 0; h < 128; ++h)
                acc += W1[h * 128 + i] * W2[o * 128 + h];
            M[i * OUT_CH + o] = acc;
        } else if (tid < IN_CH * OUT_CH + OUT_CH) {
            int o = tid - IN_CH * OUT_CH;
            float acc = 0.f;
            for (int h = 0; h < 128; ++h)
                acc += b1[h] * W2[o * 128 + h];
            c[o] = acc;
        }
        return;
    }
    // ---- hist ----
    int hb = b - MC_BLOCKS;
    int chunk = hb & (NCHUNK - 1);
    int range = hb >> LGCHUNK;

    int range_size = (n_nodes + NRANGE - 1) / NRANGE;
    int lo = range * range_size;
    int hi = lo + range_size; if (hi > n_nodes) hi = n_nodes;
    int nbins = hi - lo;
    if (nbins <= 0) return;

    if (threadIdx.x == 0) s_stride = detect_stride(ei);
    for (int i = threadIdx.x; i < nbins; i += 256) bins[i] = 0u;
    __syncthreads();
    int stride = s_stride;

    size_t e0 = (size_t)chunk * n_edges / NCHUNK;
    size_t e1 = (size_t)(chunk + 1) * n_edges / NCHUNK;
    size_t cnt = e1 - e0;
    const int* rp = ei;
    const int* cp = ei + (size_t)n_edges * stride;

    size_t i = threadIdx.x;
    for (; i + 768 < cnt; i += 1024) {
        int s0 = rp[(e0 + i) * stride];
        int s1 = rp[(e0 + i + 256) * stride];
        int s2 = rp[(e0 + i + 512) * stride];
        int s3 = rp[(e0 + i + 768) * stride];
        int d0 = cp[(e0 + i) * stride];
        int d1 = cp[(e0 + i + 256) * stride];
        int d2 = cp[(e0 + i + 512) * stride];
        int d3 = cp[(e0 + i + 768) * stride];
        if (s0 >= lo && s0 < hi) atomicAdd(&bins[s0 - lo], 1u);
        if (s1 >= lo && s1 < hi) atomicAdd(&bins[s1 - lo], 1u);
        if (s2 >= lo && s2 < hi) atomicAdd(&bins[s2 - lo], 1u);
        if (s3 >= lo && s3 < hi) atomicAdd(&bins[s3 - lo], 1u);
        if (d0 >= lo && d0 < hi && (unsigned)s0 < (unsigned)n_nodes) atomicAdd(&bins[d0 - lo], 0x10000u);
        if (d1 >= lo && d1 < hi && (unsigned)s1 < (unsigned)n_nodes) atomicAdd(&bins[d1 - lo], 0x10000u);
        if (d2 >= lo && d2 < hi && (unsigned)s2 < (unsigned)n_nodes) atomicAdd(&bins[d2 - lo], 0x10000u);
        if (d3 >= lo && d3 < hi && (unsigned)s3 < (unsigned)n_nodes) atomicAdd(&bins[d3 - lo], 0x10000u);
    }
    for (; i < cnt; i += 256) {
        int s = rp[(e0 + i) * stride];
        int d = cp[(e0 + i) * stride];
        if (s >= lo && s < hi) atomicAdd(&bins[s - lo], 1u);
        if (d >= lo && d < hi && (unsigned)s < (unsigned)n_nodes) atomicAdd(&bins[d - lo], 0x10000u);
    }
    __syncthreads();

    size_t base = (size_t)chunk * n_nodes + lo;
    for (int k = threadIdx.x; k < nbins; k += 256) {
        u32 v = bins[k];
        row_slab[base + k] = (u16)(v & 0xFFFFu);
        col_slab[base + k] = (u16)(v >> 16);
    }
}

// ================= K2: [y | choff_scan] =================
__global__ __launch_bounds__(256) void mk_y_choff(const float* __restrict__ x,
                                                  const float* __restrict__ M,
                                                  u16* __restrict__ y,
                                                  u16* __restrict__ row_slab,
                                                  u16* __restrict__ col_slab,
                                                  int* __restrict__ deg_row,
                                                  int* __restrict__ cnt_col,
                                                  int* __restrict__ cursor_part,
                                                  int* __restrict__ bsums,
                                                  int n_nodes, int y_blocks) {
    __shared__ float smem[IN_CH * OUT_CH + 64 * (IN_CH + 4)];  // 66.6 KB
    int b = blockIdx.x;
    int tid = threadIdx.x;

    if (b < y_blocks) {
        float* Ms = smem;
        float (*xs)[IN_CH + 4] = (float(*)[IN_CH + 4])(smem + IN_CH * OUT_CH);
        int tx = tid & 15;
        int ty = tid >> 4;
        int row0 = b * 64;

        const float4* Mv = (const float4*)M;
        float4* Msv = (float4*)Ms;
#pragma unroll
        for (int k = 0; k < 8; ++k) Msv[tid + 256 * k] = Mv[tid + 256 * k];

        for (int f = tid; f < 64 * 32; f += 256) {
            int r = f >> 5, kq = f & 31;
            float4 v = make_float4(0.f, 0.f, 0.f, 0.f);
            if (row0 + r < n_nodes)
                v = *(const float4*)&x[(size_t)(row0 + r) * IN_CH + 4 * kq];
            *(float4*)&xs[r][4 * kq] = v;
        }
        __syncthreads();

        float4 acc[4];
#pragma unroll
        for (int j = 0; j < 4; ++j) acc[j] = make_float4(0.f, 0.f, 0.f, 0.f);

        for (int k = 0; k < IN_CH; k += 4) {
            float4 xr[4], mr[4];
#pragma unroll
            for (int j = 0; j < 4; ++j)
                xr[j] = *(const float4*)&xs[4 * ty + j][k];
#pragma unroll
            for (int kk = 0; kk < 4; ++kk)
                mr[kk] = *(const float4*)&Ms[(k + kk) * OUT_CH + 4 * tx];
#pragma unroll
            for (int j = 0; j < 4; ++j) {
                acc[j].x = fmaf(xr[j].x, mr[0].x, acc[j].x);
                acc[j].y = fmaf(xr[j].x, mr[0].y, acc[j].y);
                acc[j].z = fmaf(xr[j].x, mr[0].z, acc[j].z);
                acc[j].w = fmaf(xr[j].x, mr[0].w, acc[j].w);
                acc[j].x = fmaf(xr[j].y, mr[1].x, acc[j].x);
                acc[j].y = fmaf(xr[j].y, mr[1].y, acc[j].y);
                acc[j].z = fmaf(xr[j].y, mr[1].z, acc[j].z);
                acc[j].w = fmaf(xr[j].y, mr[1].w, acc[j].w);
                acc[j].x = fmaf(xr[j].z, mr[2].x, acc[j].x);
                acc[j].y = fmaf(xr[j].z, mr[2].y, acc[j].y);
                acc[j].z = fmaf(xr[j].z, mr[2].z, acc[j].z);
                acc[j].w = fmaf(xr[j].z, mr[2].w, acc[j].w);
                acc[j].x = fmaf(xr[j].w, mr[3].x, acc[j].x);
                acc[j].y = fmaf(xr[j].w, mr[3].y, acc[j].y);
                acc[j].z = fmaf(xr[j].w, mr[3].z, acc[j].z);
                acc[j].w = fmaf(xr[j].w, mr[3].w, acc[j].w);
            }
        }

#pragma unroll
        for (int j = 0; j < 4; ++j) {
            int r = row0 + 4 * ty + j;
            if (r < n_nodes) {
                ushort4 s4;
                s4.x = f2bf(acc[j].x);
                s4.y = f2bf(acc[j].y);
                s4.z = f2bf(acc[j].z);
                s4.w = f2bf(acc[j].w);
                *(ushort4*)&y[(size_t)r * OUT_CH + 4 * tx] = s4;
            }
        }
        return;
    }

    // ---- choff_scan ----
    int* sm = (int*)smem;
    int t = tid;
    int n = (b - y_blocks) * 256 + t;
    int run = 0;
    if (n < n_nodes) {
        int sum = 0;
#pragma unroll 8
        for (int ch = 0; ch < NCHUNK; ++ch)
            sum += row_slab[(size_t)ch * n_nodes + n];
        deg_row[n] = sum;
#pragma unroll 8
        for (int ch = 0; ch < NCHUNK; ++ch) {
            int v = col_slab[(size_t)ch * n_nodes + n];
            col_slab[(size_t)ch * n_nodes + n] = (u16)run;
            run += v;
        }
        cnt_col[n] = run;
    }
    sm[t] = run;
    __syncthreads();
    for (int d = 1; d < 256; d <<= 1) {
        int add = (t >= d) ? sm[t - d] : 0;
        __syncthreads();
        sm[t] += add;
        __syncthreads();
    }
    if (n < n_nodes) cursor_part[n] = sm[t] - run;
    if (t == 255) bsums[b - y_blocks] = sm[t];
}

// in-block exclusive scan of bsums[0..nb) into bscan LDS (nb <= 256)
static __device__ inline void block_bscan(const int* __restrict__ bsums, int nb,
                                          int* __restrict__ bscan) {
    int t = threadIdx.x;
    int v = (t < nb) ? bsums[t] : 0;
    bscan[t] = v;
    __syncthreads();
    for (int d = 1; d < 256; d <<= 1) {
        int add = (t >= d) ? bscan[t - d] : 0;
        __syncthreads();
        bscan[t] += add;
        __syncthreads();
    }
    bscan[t] -= v;   // exclusive
    __syncthreads();
}

// ================= K3: place =================
__global__ __launch_bounds__(256) void mk_place(const int* __restrict__ ei,
                                                const int* __restrict__ cursor_part,
                                                const int* __restrict__ bsums,
                                                const u16* __restrict__ col_slab,
                                                int* __restrict__ csr_src,
                                                int n_edges, int n_nodes, int nb) {
    __shared__ int rank[RBINS];
    __shared__ int bscan[256];
    block_bscan(bsums, nb, bscan);

    int b = blockIdx.x;
    int chunk = b & (NCHUNK - 1);
    int range = b >> LGCHUNK;

    int range_size = (n_nodes + NRANGE - 1) / NRANGE;
    int lo = range * range_size;
    int hi = lo + range_size; if (hi > n_nodes) hi = n_nodes;
    if (hi <= lo) return;

    for (int i = threadIdx.x; i < hi - lo; i += 256) rank[i] = 0;
    __syncthreads();

    int stride = detect_stride(ei);
    size_t e0 = (size_t)chunk * n_edges / NCHUNK;
    size_t e1 = (size_t)(chunk + 1) * n_edges / NCHUNK;
    size_t cnt = e1 - e0;
    const int* rp = ei;
    const int* cp = ei + (size_t)n_edges * stride;
    size_t slab_base = (size_t)chunk * n_nodes;

    size_t i = threadIdx.x;
    for (; i + 768 < cnt; i += 1024) {
        int s0 = rp[(e0 + i) * stride];
        int s1 = rp[(e0 + i + 256) * stride];
        int s2 = rp[(e0 + i + 512) * stride];
        int s3 = rp[(e0 + i + 768) * stride];
        int d0 = cp[(e0 + i) * stride];
        int d1 = cp[(e0 + i + 256) * stride];
        int d2 = cp[(e0 + i + 512) * stride];
        int d3 = cp[(e0 + i + 768) * stride];
        if (d0 >= lo && d0 < hi && (unsigned)s0 < (unsigned)n_nodes) {
            int r = atomicAdd(&rank[d0 - lo], 1);
            csr_src[cursor_part[d0] + bscan[d0 >> 8] + (int)col_slab[slab_base + d0] + r] = s0;
        }
        if (d1 >= lo && d1 < hi && (unsigned)s1 < (unsigned)n_nodes) {
            int r = atomicAdd(&rank[d1 - lo], 1);
            csr_src[cursor_part[d1] + bscan[d1 >> 8] + (int)col_slab[slab_base + d1] + r] = s1;
        }
        if (d2 >= lo && d2 < hi && (unsigned)s2 < (unsigned)n_nodes) {
            int r = atomicAdd(&rank[d2 - lo], 1);
            csr_src[cursor_part[d2] + bscan[d2 >> 8] + (int)col_slab[slab_base + d2] + r] = s2;
        }
        if (d3 >= lo && d3 < hi && (unsigned)s3 < (unsigned)n_nodes) {
            int r = atomicAdd(&rank[d3 - lo], 1);
            csr_src[cursor_part[d3] + bscan[d3 >> 8] + (int)col_slab[slab_base + d3] + r] = s3;
        }
    }
    for (; i < cnt; i += 256) {
        int s = rp[(e0 + i) * stride];
        int d = cp[(e0 + i) * stride];
        if (d >= lo && d < hi && (unsigned)s < (unsigned)n_nodes) {
            int r = atomicAdd(&rank[d - lo], 1);
            csr_src[cursor_part[d] + bscan[d >> 8] + (int)col_slab[slab_base + d] + r] = s;
        }
    }
}

// ================= K4: agg_final (2 dsts/wave, dword gather) =================
__global__ __launch_bounds__(256) void mk_agg_final(const int* __restrict__ cursor_part,
                                                    const int* __restrict__ bsums,
                                                    const int* __restrict__ cnt_col,
                                                    const int* __restrict__ csr_src,
                                                    const int* __restrict__ deg_row,
                                                    const u32* __restrict__ y,   // bf16x2
                                                    const float* __restrict__ c,
                                                    const float* __restrict__ b2,
                                                    float* __restrict__ out,
                                                    int n_nodes, int nb) {
    __shared__ int bscan[256];
    block_bscan(bsums, nb, bscan);

    int wave = threadIdx.x >> 6;
    int half = (threadIdx.x >> 5) & 1;
    int sub  = threadIdx.x & 31;          // channel pair index
    int d = blockIdx.x * 8 + wave * 2 + half;
    if (d >= n_nodes) return;

    int start = cursor_part[d] + bscan[d >> 8];
    int cnt = cnt_col[d];
    int end = start + cnt;
    float ax = 0.f, ay = 0.f;
    int e1m = end - 1;
    for (int j = start; j < end; j += 8) {
        int i1 = j + 1 > e1m ? e1m : j + 1;
        int i2 = j + 2 > e1m ? e1m : j + 2;
        int i3 = j + 3 > e1m ? e1m : j + 3;
        int i4 = j + 4 > e1m ? e1m : j + 4;
        int i5 = j + 5 > e1m ? e1m : j + 5;
        int i6 = j + 6 > e1m ? e1m : j + 6;
        int i7 = j + 7 > e1m ? e1m : j + 7;
        int s0 = csr_src[j];
        int s1 = csr_src[i1];
        int s2 = csr_src[i2];
        int s3 = csr_src[i3];
        int s4 = csr_src[i4];
        int s5 = csr_src[i5];
        int s6 = csr_src[i6];
        int s7 = csr_src[i7];
        u32 u0 = y[(size_t)s0 * 32 + sub];
        u32 u1 = y[(size_t)s1 * 32 + sub];
        u32 u2 = y[(size_t)s2 * 32 + sub];
        u32 u3 = y[(size_t)s3 * 32 + sub];
        u32 u4 = y[(size_t)s4 * 32 + sub];
        u32 u5 = y[(size_t)s5 * 32 + sub];
        u32 u6 = y[(size_t)s6 * 32 + sub];
        u32 u7 = y[(size_t)s7 * 32 + sub];
        u1 = (j + 1 < end) ? u1 : 0u;
        u2 = (j + 2 < end) ? u2 : 0u;
        u3 = (j + 3 < end) ? u3 : 0u;
        u4 = (j + 4 < end) ? u4 : 0u;
        u5 = (j + 5 < end) ? u5 : 0u;
        u6 = (j + 6 < end) ? u6 : 0u;
        u7 = (j + 7 < end) ? u7 : 0u;
        ax += ((bfu32_lo(u0) + bfu32_lo(u1)) + (bfu32_lo(u2) + bfu32_lo(u3)))
            + ((bfu32_lo(u4) + bfu32_lo(u5)) + (bfu32_lo(u6) + bfu32_lo(u7)));
        ay += ((bfu32_hi(u0) + bfu32_hi(u1)) + (bfu32_hi(u2) + bfu32_hi(u3)))
            + ((bfu32_hi(u4) + bfu32_hi(u5)) + (bfu32_hi(u6) + bfu32_hi(u7)));
    }
    int dr = deg_row[d];
    float di = (dr > 0) ? (1.0f / (float)dr) : 0.f;
    float2 cv = *(const float2*)&c[2 * sub];
    float2 bv = *(const float2*)&b2[2 * sub];
    float2 o;
    o.x = di * ax + di * (float)cnt * cv.x + bv.x;
    o.y = di * ay + di * (float)cnt * cv.y + bv.y;
    *(float2*)&out[(size_t)d * OUT_CH + 2 * sub] = o;
}

extern "C" void kernel_launch(void* const* d_in, const int* in_sizes, int n_in,
                              void* d_out, int out_size, void* d_ws, size_t ws_size,
                              hipStream_t stream) {
    const float* x  = (const float*)d_in[0];
    const int*   ei = (const int*)d_in[1];
    const float* W1 = (const float*)d_in[2];
    const float* b1 = (const float*)d_in[3];
    const float* W2 = (const float*)d_in[4];
    const float* b2 = (const float*)d_in[5];
    float* out = (float*)d_out;

    const int n_nodes = in_sizes[0] / IN_CH;     // 50000
    const int n_edges = in_sizes[1] / 2;         // 800000

    const size_t slab_bytes = (((size_t)NCHUNK * n_nodes * 2) + 127) & ~(size_t)127;
    const size_t csr_bytes  = ((size_t)n_edges * 4 + 127) & ~(size_t)127;

    char* ws = (char*)d_ws;
    float* M        = (float*)(ws);                    // 32768
    float* c        = (float*)(ws + 32768);            // 256
    int*   deg_row  = (int*)  (ws + 33152);            // 200064
    int*   cnt_col  = (int*)  (ws + 233216);           // 200064
    int*   cursor   = (int*)  (ws + 433280);           // 200064 (cursor_part)
    int*   bsums    = (int*)  (ws + 633344);           // 4096
    u16*   row_slab = (u16*)  (ws + 637440);           // 6.4 MB
    u16*   col_slab = (u16*)  (ws + 637440 + slab_bytes);
    int*   csr_src  = (int*)  (ws + 637440 + 2 * slab_bytes);
    u16*   y        = (u16*)  (ws + 637440 + 2 * slab_bytes + csr_bytes);

    const int y_blocks = (n_nodes + 63) / 64;          // 782
    const int nb = (n_nodes + 255) / 256;              // 196  (<=256 required)

    mk_prep<<<MC_BLOCKS + NCHUNK * NRANGE, 256, 0, stream>>>(
        W1, b1, W2, ei, M, c, row_slab, col_slab, n_edges, n_nodes);

    mk_y_choff<<<y_blocks + nb, 256, 0, stream>>>(
        x, M, y, row_slab, col_slab, deg_row, cnt_col, cursor, bsums,
        n_nodes, y_blocks);

    mk_place<<<NCHUNK * NRANGE, 256, 0, stream>>>(
        ei, cursor, bsums, col_slab, csr_src, n_edges, n_nodes, nb);

    mk_agg_final<<<(n_nodes + 7) / 8, 256, 0, stream>>>(
        cursor, bsums, cnt_col, csr_src, deg_row, (const u32*)y, c, b2, out,
        n_nodes, nb);
}